// Round 3
// baseline (27.605 us; speedup 1.0000x reference)
//
#include <hip/hip_runtime.h>

// x: (512, 2048, 64) f32. Per row of 64 floats we need float indices
// 0 (sign), 1 (e10), 11 (e0), 12 (m51), 13 (m50) — bytes 0..55 of each 256B row.
// Outputs flat in d_out: result (R,2) f32 then sign (R,1) f32. R = 1,048,576.
//
// 4 consecutive rows per thread: all 12 loads use one 64-bit base + immediate
// offsets (max 3*256+48 = 816B < 4096), issued back-to-back for max MLP.
// Exactly-needed segments: dwordx2@0, dword@44, dwordx2@48 per row (20B/row).
// Stores: 2x float4 (result, 32B-aligned) + 1x float4 (sign, 16B-aligned).

__global__ void __launch_bounds__(256) spike_extract_x4(
        const float* __restrict__ x,
        float* __restrict__ result,
        float* __restrict__ sign_out,
        int nrows) {
    int t = blockIdx.x * blockDim.x + threadIdx.x;
    int row0 = t << 2;
    if (row0 >= nrows) return;

    const float* base = x + ((size_t)row0 << 6);

    float2 se[4];   // {sign, e10}
    float  e0v[4];
    float2 mm[4];   // {m51, m50}

    // Issue all 12 loads up front (constant offsets -> immediate-offset loads).
#pragma unroll
    for (int r = 0; r < 4; ++r) {
        const float* p = base + (r << 6);
        se[r]  = *reinterpret_cast<const float2*>(p);       // idx 0,1
        e0v[r] = p[11];                                     // idx 11
        mm[r]  = *reinterpret_cast<const float2*>(p + 12);  // idx 12,13
    }

    float b1[4], b0[4];
#pragma unroll
    for (int r = 0; r < 4; ++r) {
        float e10 = se[r].y;
        float e0  = e0v[r];
        float m51 = mm[r].x;
        float m50 = mm[r].y;
        // _mux(sel,a,b) = b + sel*(a-b)
        float b0_high = fmaf(e0, m50 - m51, m51);     // mux(e0, m50, m51)
        float b1_high = fmaf(e0, m51 - 1.0f, 1.0f);   // mux(e0, m51, 1)
        b0[r] = fmaf(e10, b0_high - e0, e0);          // mux(e10, b0_high, e0)
        b1[r] = e10 * b1_high;                        // mux(e10, b1_high, 0)
    }

    // result rows row0..row0+3 -> 8 consecutive floats, 32B-aligned.
    float4* rp = reinterpret_cast<float4*>(result + ((size_t)row0 << 1));
    rp[0] = make_float4(b1[0], b0[0], b1[1], b0[1]);
    rp[1] = make_float4(b1[2], b0[2], b1[3], b0[3]);

    *reinterpret_cast<float4*>(sign_out + row0) =
        make_float4(se[0].x, se[1].x, se[2].x, se[3].x);
}

extern "C" void kernel_launch(void* const* d_in, const int* in_sizes, int n_in,
                              void* d_out, int out_size, void* d_ws, size_t ws_size,
                              hipStream_t stream) {
    const float* x = (const float*)d_in[0];
    float* out = (float*)d_out;

    int nrows = in_sizes[0] / 64;          // 1,048,576
    float* result = out;                   // nrows * 2 floats
    float* sign_out = out + (size_t)nrows * 2;

    const int block = 256;
    const int grid = (nrows / 4 + block - 1) / block;  // 1024 blocks
    spike_extract_x4<<<grid, block, 0, stream>>>(x, result, sign_out, nrows);
}